// Round 8
// baseline (124.322 us; speedup 1.0000x reference)
//
#include <hip/hip_runtime.h>

// VQ-VAE vector quantizer, MI355X.
// z_e: [32,64,32,32] f32, codebook: [1024,64] f32.
// d_out = q_out(2097152) | loss(1) | perplexity(1) | encodings(33554432), all f32.
//
// Pipeline (3 dispatches):
//   1. vq_ensq_kernel    : codebook squared norms + hist zero
//   2. vq_argmin_kernel  : fused distances+argmin+q_out+loss+hist+encodings
//   3. vq_finalize_kernel: loss mean + perplexity
//
// argmin structure (round 8): accumulator-resident, z-streamed.
// Rounds 3-7 kept z[64] live across the whole K-loop; the allocator refused
// to give it 64 arch VGPRs (remat / AGPR-park / constraint copies ~halved
// productive VALU every time). This round the LONG-LIVED values are 32 dot
// accumulators per 32-code block; z is a short-lived 16-channel chunk
// re-loaded per code block (L1-resident 16 KB/block, coalesced, vmcnt
// pipelined). Peak live ~60 VGPR < 64-granule -> allocator is satisfied, not
// fought. Codebook feed stays wave-uniform s_load (scalar pipe: the only
// broadcast path that contends with nothing; r1 proved LDS-bound, r6 proved
// per-lane-VMEM-bound). 1024-thread blocks -> 8 waves/EU latency hiding.
//
// ws layout (4-byte units):
//   [0,1024)       hist (int)
//   [1024,2048)    ensq (float)
//   [34816,35328)  partials (float[512])

#define NROWS 32768
#define KC    1024
#define DD    64
#define HW    1024
#define CHW   65536
#define NW    16          // waves per block (1024 threads)
#define CPW   64          // codes per wave
#define CBLK  32          // codes per accumulator block

typedef float f32x2 __attribute__((ext_vector_type(2)));

__global__ __launch_bounds__(256) void vq_ensq_kernel(const float* __restrict__ cb,
                                                      float* __restrict__ ensq,
                                                      int* __restrict__ hist) {
  int k = blockIdx.x * 256 + threadIdx.x;   // 4 blocks x 256 = exactly KC
  hist[k] = 0;
  const float* row = cb + k * DD;
  float s = 0.f;
#pragma unroll
  for (int c = 0; c < DD; ++c) s = fmaf(row[c], row[c], s);
  ensq[k] = s;
}

__global__ __launch_bounds__(1024) void vq_argmin_kernel(
    const float* __restrict__ z_e, const float* __restrict__ cb,
    const float* __restrict__ ensq_g, float* __restrict__ qout,
    float* __restrict__ enc, int* __restrict__ hist,
    float* __restrict__ partials) {
  __shared__ float s_val[NW][64];
  __shared__ int   s_idx[NW][64];
  __shared__ float s_loss[NW];

  const int tid  = threadIdx.x;
  const int lane = tid & 63;
  const int wave = __builtin_amdgcn_readfirstlane(tid >> 6);  // wave-uniform
  const int n    = blockIdx.x * 64 + lane;
  const int b    = n >> 10;
  const int hw   = n & (HW - 1);
  const float* zp = z_e + (size_t)b * CHW + hw;

  // ||z||^2: sequential fmaf chain c=0..63 (bit-identical to prior rounds).
  float zsq = 0.f;
#pragma unroll
  for (int c = 0; c < DD; ++c) {
    float zc = zp[(size_t)c << 10];
    zsq = fmaf(zc, zc, zsq);
  }

  // Streaming zero-fill of this block's encodings slice (64 rows x 1024 f32 =
  // 32768 f32x2): 32 slots/thread, 4 per main-loop iteration (8 iterations).
  f32x2* myenc = (f32x2*)(enc + (size_t)blockIdx.x * 64 * KC);

  // This wave scans codes [kw, kw+64) in two 32-code accumulator blocks.
  const int kw = wave * CPW;
  float bestd = 3.402823466e38f;
  int   besti = 0;

#pragma unroll
  for (int cb4 = 0; cb4 < CPW / CBLK; ++cb4) {
    const int kg = kw + cb4 * CBLK;
    float acc[CBLK];
#pragma unroll
    for (int j = 0; j < CBLK; ++j) acc[j] = 0.f;

#pragma unroll
    for (int ch = 0; ch < 4; ++ch) {     // 16-channel chunks, ascending c
      {
        const int it = cb4 * 4 + ch;     // 0..7
        f32x2 zz2 = {0.f, 0.f};
#pragma unroll
        for (int q = 0; q < 4; ++q)
          __builtin_nontemporal_store(zz2, &myenc[it * 4096 + q * 1024 + tid]);
      }
      // short-lived z chunk: 16 coalesced dword loads, L1-hot after 1st pass
      float zz[16];
#pragma unroll
      for (int i = 0; i < 16; ++i) zz[i] = zp[(size_t)(ch * 16 + i) << 10];
      // 32 independent fmaf chains; e-elements wave-uniform -> s_load_dwordx16
#pragma unroll
      for (int j = 0; j < CBLK; ++j) {
        const float* p = cb + (size_t)(kg + j) * DD + ch * 16;
#pragma unroll
        for (int i = 0; i < 16; ++i) acc[j] = fmaf(zz[i], p[i], acc[j]);
      }
    }

    // mimic ref rounding: (||z||^2 + ||e||^2) - 2*(z.e), all fp32
#pragma unroll
    for (int j = 0; j < CBLK; ++j) {
      float d = (zsq + ensq_g[kg + j]) - 2.f * acc[j];
      if (d < bestd) { bestd = d; besti = kg + j; }
    }
  }

  s_val[wave][lane] = bestd;
  s_idx[wave][lane] = besti;
  __syncthreads();   // also drains (vmcnt 0) the zero-fill stores

  // cross-wave argmin reduce (ascending code ranges; tie -> lower index) +
  // one-hot 1.0 scatter (zeros for these addresses completed at the barrier)
  if (wave == 0) {
    float bd = s_val[0][lane];
    int   bi = s_idx[0][lane];
#pragma unroll
    for (int w2 = 1; w2 < NW; ++w2) {
      float d  = s_val[w2][lane];
      int   i2 = s_idx[w2][lane];
      if (d < bd || (d == bd && i2 < bi)) { bd = d; bi = i2; }
    }
    s_idx[0][lane] = bi;   // broadcast final index
    atomicAdd(&hist[bi], 1);
    enc[(size_t)n * KC + bi] = 1.0f;
  }
  __syncthreads();

  // fused epilogue: q_out write + loss partial. Each wave handles 4 channels
  // for all 64 rows of the block. z reloaded from global (L1-hot).
  const int bif = s_idx[0][lane];
  const float* cbrow = cb + (size_t)bif * DD;
  float* qp = qout + (size_t)b * CHW + hw;
  float lacc = 0.f;
#pragma unroll
  for (int j = 0; j < DD / NW; ++j) {
    int c = wave * (DD / NW) + j;
    float v    = cbrow[c];
    float zc   = zp[(size_t)c << 10];
    float diff = v - zc;               // matches ref (quantized - ze)
    qp[(size_t)c << 10] = zc + diff;   // matches ref ze + (quantized - ze)
    lacc = fmaf(diff, diff, lacc);
  }
#pragma unroll
  for (int off = 32; off > 0; off >>= 1) lacc += __shfl_down(lacc, off, 64);
  if (lane == 0) s_loss[wave] = lacc;
  __syncthreads();
  if (tid == 0) {
    float t = 0.f;
#pragma unroll
    for (int w2 = 0; w2 < NW; ++w2) t += s_loss[w2];
    partials[blockIdx.x] = t;
  }
}

__global__ __launch_bounds__(1024) void vq_finalize_kernel(
    const int* __restrict__ hist, const float* __restrict__ partials,
    float* __restrict__ out_loss, float* __restrict__ out_ppl) {
  __shared__ float red[1024];
  const int t = threadIdx.x;

  // entropy term
  float p   = (float)hist[t] * (1.0f / 32768.0f);
  float ent = p * logf(p + 1e-10f);
  red[t] = ent;
  __syncthreads();
  for (int s = 512; s > 0; s >>= 1) {
    if (t < s) red[t] += red[t + s];
    __syncthreads();
  }
  float entropy = red[0];
  __syncthreads();

  // loss sum
  red[t] = (t < 512) ? partials[t] : 0.f;
  __syncthreads();
  for (int s = 512; s > 0; s >>= 1) {
    if (t < s) red[t] += red[t + s];
    __syncthreads();
  }
  if (t == 0) {
    *out_loss = 0.25f * (red[0] * (1.0f / 2097152.0f));
    *out_ppl  = expf(-entropy);
  }
}

extern "C" void kernel_launch(void* const* d_in, const int* in_sizes, int n_in,
                              void* d_out, int out_size, void* d_ws, size_t ws_size,
                              hipStream_t stream) {
  const float* z_e = (const float*)d_in[0];
  const float* cb  = (const float*)d_in[1];

  float* out  = (float*)d_out;
  float* qout = out;                       // 2097152
  float* loss = out + 2097152;
  float* ppl  = out + 2097153;
  float* enc  = out + 2097154;             // 33554432 floats

  int*   hist     = (int*)d_ws;
  float* ensq     = (float*)d_ws + 1024;
  float* partials = (float*)d_ws + 34816;

  vq_ensq_kernel<<<4, 256, 0, stream>>>(cb, ensq, hist);
  vq_argmin_kernel<<<512, 1024, 0, stream>>>(z_e, cb, ensq, qout, enc, hist, partials);
  vq_finalize_kernel<<<1, 1024, 0, stream>>>(hist, partials, loss, ppl);
}